// Round 1
// baseline (654.051 us; speedup 1.0000x reference)
//
#include <hip/hip_runtime.h>
#include <cstdio>
#include <cstdint>

#define SEQ 4096
#define NB 4
#define DIM 1024
#define MTOT (NB * SEQ)   // 16384

using u16x8  = __attribute__((ext_vector_type(8))) unsigned short;
using bf16x8 = __attribute__((ext_vector_type(8))) __bf16;
using f32x4  = __attribute__((ext_vector_type(4))) float;

__device__ __forceinline__ unsigned short f2bf(float f) {
  unsigned u = __builtin_bit_cast(unsigned, f);
  u += 0x7fffu + ((u >> 16) & 1u);          // round-to-nearest-even
  return (unsigned short)(u >> 16);
}
__device__ __forceinline__ float bf2f(unsigned short h) {
  return __builtin_bit_cast(float, (unsigned)h << 16);
}

// async global->LDS, 16B per lane; LDS dest is wave-uniform base + lane*16
__device__ __forceinline__ void gload16(const void* g, void* l) {
  __builtin_amdgcn_global_load_lds(
      (const __attribute__((address_space(1))) unsigned int*)g,
      (__attribute__((address_space(3))) unsigned int*)l, 16, 0, 0);
}

// ---------------- convert x fp32 -> bf16 ----------------
__global__ __launch_bounds__(256) void cvt_x(const float* __restrict__ in,
                                             unsigned short* __restrict__ out) {
  size_t i = ((size_t)blockIdx.x * 256 + threadIdx.x) * 4;
  float4 v = *(const float4*)(in + i);
  ushort4 o;
  o.x = f2bf(v.x); o.y = f2bf(v.y); o.z = f2bf(v.z); o.w = f2bf(v.w);
  *(ushort4*)(out + i) = o;
}

// ---------------- W fp32 [1024][1024] -> WT bf16 [1024][1024] ----------------
__global__ __launch_bounds__(256) void transpose_w(const float* __restrict__ W,
                                                   unsigned short* __restrict__ WT) {
  __shared__ float tile[32][33];
  const int tx = threadIdx.x, ty = threadIdx.y;
  const int d0 = blockIdx.y * 32, e0 = blockIdx.x * 32;
#pragma unroll
  for (int j = 0; j < 32; j += 8)
    tile[ty + j][tx] = W[(size_t)(d0 + ty + j) * DIM + e0 + tx];
  __syncthreads();
#pragma unroll
  for (int j = 0; j < 32; j += 8)
    WT[(size_t)(e0 + ty + j) * DIM + d0 + tx] = f2bf(tile[tx][ty + j]);
}

// ---------------- BT-form GEMM: C[M,N] = A[M,K] * B^T (B stored [N,K]) ----------------
// 128x128 tile, BK=32, 256 threads (4 waves, 2x2 of 64x64), 16x16x32 bf16 MFMA.
enum { EPI_QK = 0, EPI_VT = 1, EPI_SCALE = 2, EPI_F32 = 3 };

template <int EPI>
__global__ __launch_bounds__(256) void gemm_bt(
    const unsigned short* __restrict__ A, long sA,
    const unsigned short* __restrict__ B, long sB,
    void* __restrict__ C, long sC,
    const float* __restrict__ bias,
    int K, int lda, int ldb, int ldc, float scale) {
  __shared__ unsigned short As[128 * 32];
  __shared__ unsigned short Bs[128 * 32];
  const int t = threadIdx.x;
  const int lane = t & 63;
  const int wave = t >> 6;
  const size_t row0 = (size_t)blockIdx.x * 128;
  const size_t col0 = (size_t)blockIdx.y * 128;
  const unsigned short* Ab = A + (size_t)blockIdx.z * (size_t)sA;
  const unsigned short* Bb = B + (size_t)blockIdx.z * (size_t)sB;

  const int wm = (wave >> 1) * 64;
  const int wn = (wave & 1) * 64;
  const int fr = lane & 15;          // frag row (A) / col (B) / col (C)
  const int fk = (lane >> 4) * 8;    // frag k offset

  f32x4 acc[4][4];
  const f32x4 z4 = {0.f, 0.f, 0.f, 0.f};
#pragma unroll
  for (int i = 0; i < 4; ++i)
#pragma unroll
    for (int j = 0; j < 4; ++j) acc[i][j] = z4;

  // staging: tile row = t>>2 (+64 for 2nd load), 16B segment = t&3
  const int srow = t >> 2;
  const int sseg = (t & 3) * 8;
  const unsigned short* gA = Ab + (row0 + srow) * (size_t)lda + sseg;
  const unsigned short* gB = Bb + (col0 + srow) * (size_t)ldb + sseg;
  unsigned short* lA = As + wave * 512;   // wave-uniform LDS base (bytes = wave*1024)
  unsigned short* lB = Bs + wave * 512;
  const size_t a64 = (size_t)64 * lda;
  const size_t b64 = (size_t)64 * ldb;

  for (int k0 = 0; k0 < K; k0 += 32) {
    gload16(gA + k0, lA);
    gload16(gA + k0 + a64, lA + 2048);
    gload16(gB + k0, lB);
    gload16(gB + k0 + b64, lB + 2048);
    __syncthreads();   // drains vmcnt(0) + barrier -> LDS tile ready
    bf16x8 af[4], bfr[4];
#pragma unroll
    for (int mi = 0; mi < 4; ++mi)
      af[mi] = *(const bf16x8*)(As + (wm + mi * 16 + fr) * 32 + fk);
#pragma unroll
    for (int ni = 0; ni < 4; ++ni)
      bfr[ni] = *(const bf16x8*)(Bs + (wn + ni * 16 + fr) * 32 + fk);
#pragma unroll
    for (int mi = 0; mi < 4; ++mi)
#pragma unroll
      for (int ni = 0; ni < 4; ++ni)
        acc[mi][ni] = __builtin_amdgcn_mfma_f32_16x16x32_bf16(af[mi], bfr[ni], acc[mi][ni], 0, 0, 0);
    __syncthreads();   // all waves done reading before next stage overwrites
  }

  // C/D frag layout (m89-verified): col = lane&15, row = (lane>>4)*4 + j
  const int rb = (lane >> 4) * 4;
  if constexpr (EPI == EPI_F32) {
    float* Co = (float*)C + (size_t)blockIdx.z * (size_t)sC;
#pragma unroll
    for (int mi = 0; mi < 4; ++mi) {
      size_t gr = row0 + wm + mi * 16 + rb;
#pragma unroll
      for (int ni = 0; ni < 4; ++ni) {
        size_t gc = col0 + wn + ni * 16 + fr;
#pragma unroll
        for (int j = 0; j < 4; ++j)
          Co[(gr + j) * (size_t)ldc + gc] = acc[mi][ni][j];
      }
    }
  } else if constexpr (EPI == EPI_SCALE) {
    unsigned short* Co = (unsigned short*)C + (size_t)blockIdx.z * (size_t)sC;
#pragma unroll
    for (int mi = 0; mi < 4; ++mi) {
      size_t gr = row0 + wm + mi * 16 + rb;
#pragma unroll
      for (int ni = 0; ni < 4; ++ni) {
        size_t gc = col0 + wn + ni * 16 + fr;
#pragma unroll
        for (int j = 0; j < 4; ++j)
          Co[(gr + j) * (size_t)ldc + gc] = f2bf(acc[mi][ni][j] * scale);
      }
    }
  } else if constexpr (EPI == EPI_QK) {
    unsigned short* Co = (unsigned short*)C;
#pragma unroll
    for (int ni = 0; ni < 4; ++ni) {
      size_t gc = col0 + wn + ni * 16 + fr;
      float bb = bias[gc];
#pragma unroll
      for (int mi = 0; mi < 4; ++mi) {
        size_t gr = row0 + wm + mi * 16 + rb;
#pragma unroll
        for (int j = 0; j < 4; ++j)
          Co[(gr + j) * (size_t)ldc + gc] = f2bf(acc[mi][ni][j] + bb);
      }
    }
  } else {  // EPI_VT: store transposed, C[gc][gr], 4 consecutive rows -> 8B store
    unsigned short* Co = (unsigned short*)C;
#pragma unroll
    for (int ni = 0; ni < 4; ++ni) {
      size_t gc = col0 + wn + ni * 16 + fr;
      float bb = bias[gc];
#pragma unroll
      for (int mi = 0; mi < 4; ++mi) {
        size_t gr = row0 + wm + mi * 16 + rb;
        ushort4 pk;
        pk.x = f2bf(acc[mi][ni][0] + bb);
        pk.y = f2bf(acc[mi][ni][1] + bb);
        pk.z = f2bf(acc[mi][ni][2] + bb);
        pk.w = f2bf(acc[mi][ni][3] + bb);
        *(ushort4*)(Co + gc * (size_t)ldc + gr) = pk;
      }
    }
  }
}

// ---------------- row softmax in place on bf16 S rows of 4096 ----------------
__global__ __launch_bounds__(256) void softmax_rows(unsigned short* __restrict__ S, long sB) {
  const int t = threadIdx.x;
  unsigned short* row = S + (size_t)blockIdx.y * (size_t)sB + (size_t)blockIdx.x * SEQ;
  u16x8 a = *(const u16x8*)(row + t * 16);
  u16x8 b = *(const u16x8*)(row + t * 16 + 8);
  float v[16];
#pragma unroll
  for (int j = 0; j < 8; ++j) { v[j] = bf2f(a[j]); v[j + 8] = bf2f(b[j]); }
  float m = v[0];
#pragma unroll
  for (int j = 1; j < 16; ++j) m = fmaxf(m, v[j]);
  for (int off = 32; off > 0; off >>= 1) m = fmaxf(m, __shfl_xor(m, off));
  __shared__ float redm[4], reds[4];
  const int w = t >> 6;
  if ((t & 63) == 0) redm[w] = m;
  __syncthreads();
  m = fmaxf(fmaxf(redm[0], redm[1]), fmaxf(redm[2], redm[3]));
  float s = 0.f;
#pragma unroll
  for (int j = 0; j < 16; ++j) { v[j] = __expf(v[j] - m); s += v[j]; }
  for (int off = 32; off > 0; off >>= 1) s += __shfl_xor(s, off);
  if ((t & 63) == 0) reds[w] = s;
  __syncthreads();
  s = reds[0] + reds[1] + reds[2] + reds[3];
  float inv = 1.f / s;
#pragma unroll
  for (int j = 0; j < 8; ++j) { a[j] = f2bf(v[j] * inv); b[j] = f2bf(v[j + 8] * inv); }
  *(u16x8*)(row + t * 16) = a;
  *(u16x8*)(row + t * 16 + 8) = b;
}

extern "C" void kernel_launch(void* const* d_in, const int* in_sizes, int n_in,
                              void* d_out, int out_size, void* d_ws, size_t ws_size,
                              hipStream_t stream) {
  (void)in_sizes; (void)n_in; (void)out_size;
  const float* x  = (const float*)d_in[0];
  const float* Wq = (const float*)d_in[1];
  const float* bq = (const float*)d_in[2];
  const float* Wk = (const float*)d_in[3];
  const float* bk = (const float*)d_in[4];
  const float* Wv = (const float*)d_in[5];
  const float* bv = (const float*)d_in[6];
  float* out = (float*)d_out;

  const size_t EL   = (size_t)MTOT * DIM;        // 16,777,216 elems per Q/K/VT buffer
  const size_t SALL = (size_t)NB * SEQ * SEQ;    // all-batch S elems
  const size_t WEL  = (size_t)3 * DIM * DIM;
  unsigned short* Q  = (unsigned short*)d_ws;
  unsigned short* Km = Q + EL;
  unsigned short* VT = Km + EL;                  // stored transposed: VT[e][b*SEQ+s]
  unsigned short* Sb = VT + EL;
  const bool allS = ws_size >= 2 * (3 * EL + SALL + WEL);   // 241 MB
  unsigned short* WT = Sb + (allS ? SALL : EL);
  unsigned short* xb = Sb;                       // x_bf16 overlaps S region (dead after proj)

  fprintf(stderr, "[selfattn] ws_size=%zu allS=%d\n", ws_size, (int)allS);

  cvt_x<<<dim3(EL / 1024), dim3(256), 0, stream>>>(x, xb);
  transpose_w<<<dim3(32, 32), dim3(32, 8), 0, stream>>>(Wq, WT);
  transpose_w<<<dim3(32, 32), dim3(32, 8), 0, stream>>>(Wk, WT + DIM * DIM);
  transpose_w<<<dim3(32, 32), dim3(32, 8), 0, stream>>>(Wv, WT + 2 * DIM * DIM);

  dim3 gp(MTOT / 128, DIM / 128, 1);
  gemm_bt<EPI_QK><<<gp, 256, 0, stream>>>(xb, 0, WT, 0, Q, 0, bq, DIM, DIM, DIM, DIM, 1.f);
  gemm_bt<EPI_QK><<<gp, 256, 0, stream>>>(xb, 0, WT + DIM * DIM, 0, Km, 0, bk, DIM, DIM, DIM, DIM, 1.f);
  gemm_bt<EPI_VT><<<gp, 256, 0, stream>>>(xb, 0, WT + 2 * DIM * DIM, 0, VT, 0, bv, DIM, DIM, DIM, MTOT, 1.f);

  const float sc = 0.03125f;   // 1/sqrt(1024)
  if (allS) {
    gemm_bt<EPI_SCALE><<<dim3(SEQ / 128, SEQ / 128, NB), 256, 0, stream>>>(
        Q, (long)SEQ * DIM, Km, (long)SEQ * DIM, Sb, (long)SEQ * SEQ, nullptr,
        DIM, DIM, DIM, SEQ, sc);
    softmax_rows<<<dim3(SEQ, NB), 256, 0, stream>>>(Sb, (long)SEQ * SEQ);
    gemm_bt<EPI_F32><<<dim3(SEQ / 128, DIM / 128, NB), 256, 0, stream>>>(
        Sb, (long)SEQ * SEQ, VT, (long)SEQ, out, (long)SEQ * DIM, nullptr,
        SEQ, SEQ, MTOT, DIM, 1.f);
  } else {
    for (int b = 0; b < NB; ++b) {
      gemm_bt<EPI_SCALE><<<dim3(SEQ / 128, SEQ / 128, 1), 256, 0, stream>>>(
          Q + (size_t)b * SEQ * DIM, 0, Km + (size_t)b * SEQ * DIM, 0, Sb, 0, nullptr,
          DIM, DIM, DIM, SEQ, sc);
      softmax_rows<<<dim3(SEQ, 1), 256, 0, stream>>>(Sb, 0);
      gemm_bt<EPI_F32><<<dim3(SEQ / 128, DIM / 128, 1), 256, 0, stream>>>(
          Sb, 0, VT + (size_t)b * SEQ, 0, out + (size_t)b * SEQ * DIM, 0, nullptr,
          SEQ, SEQ, MTOT, DIM, 1.f);
    }
  }
}

// Round 2
// 449.442 us; speedup vs baseline: 1.4553x; 1.4553x over previous
//
#include <hip/hip_runtime.h>
#include <cstdint>

#define SEQ 4096
#define NB 4
#define DIM 1024
#define MTOT (NB * SEQ)   // 16384

using u16x8  = __attribute__((ext_vector_type(8))) unsigned short;
using bf16x8 = __attribute__((ext_vector_type(8))) __bf16;
using f32x4  = __attribute__((ext_vector_type(4))) float;

__device__ __forceinline__ unsigned short f2bf(float f) {
  unsigned u = __builtin_bit_cast(unsigned, f);
  u += 0x7fffu + ((u >> 16) & 1u);          // round-to-nearest-even
  return (unsigned short)(u >> 16);
}
__device__ __forceinline__ float bf2f(unsigned short h) {
  return __builtin_bit_cast(float, (unsigned)h << 16);
}

// async global->LDS, 16B/lane; LDS dest = wave-uniform base + lane*16
__device__ __forceinline__ void gload16(const unsigned short* g, unsigned short* l) {
  __builtin_amdgcn_global_load_lds(
      (const __attribute__((address_space(1))) unsigned int*)g,
      (__attribute__((address_space(3))) unsigned int*)l, 16, 0, 0);
}

// stage one 128x64 half-tile: 2 x (512 lanes x 16B). gsrc is per-thread
// (row srow, swizzled col already applied); ldst is wave-uniform.
__device__ __forceinline__ void stage_half(const unsigned short* gsrc, size_t ld,
                                           unsigned short* ldst) {
  gload16(gsrc, ldst);
  gload16(gsrc + 64 * ld, ldst + 64 * 64);
}

#define BAR()   __builtin_amdgcn_s_barrier()
#define FENCE() asm volatile("" ::: "memory")

// ---------------- convert x fp32 -> bf16 ----------------
__global__ __launch_bounds__(256) void cvt_x(const float* __restrict__ in,
                                             unsigned short* __restrict__ out) {
  size_t i = ((size_t)blockIdx.x * 256 + threadIdx.x) * 4;
  float4 v = *(const float4*)(in + i);
  ushort4 o;
  o.x = f2bf(v.x); o.y = f2bf(v.y); o.z = f2bf(v.z); o.w = f2bf(v.w);
  *(ushort4*)(out + i) = o;
}

// ---------------- W fp32 [1024][1024] -> WT bf16 [1024][1024] ----------------
__global__ __launch_bounds__(256) void transpose_w(const float* __restrict__ W,
                                                   unsigned short* __restrict__ WT) {
  __shared__ float tile[32][33];
  const int tx = threadIdx.x, ty = threadIdx.y;
  const int d0 = blockIdx.y * 32, e0 = blockIdx.x * 32;
#pragma unroll
  for (int j = 0; j < 32; j += 8)
    tile[ty + j][tx] = W[(size_t)(d0 + ty + j) * DIM + e0 + tx];
  __syncthreads();
#pragma unroll
  for (int j = 0; j < 32; j += 8)
    WT[(size_t)(e0 + ty + j) * DIM + d0 + tx] = f2bf(tile[tx][ty + j]);
}

// ============ 256x256 8-phase BT-GEMM: C[M,N] = A[M,K] * B^T (B stored [N,K]) ============
// 512 thr = 8 waves (2M x 4N); wave tile 128x64; BK=64; LDS 128KiB (2 K-tile bufs).
// T2 swizzle: lds_byte(row,col) = row*128 + (colbyte ^ ((row&7)<<4)); staging keeps LDS
// linear and pre-swizzles the GLOBAL source column (involution), read applies same XOR.
enum { EPI_QK = 0, EPI_VT = 1, EPI_SCALE = 2, EPI_F32 = 3 };

template <int EPI>
__global__ __launch_bounds__(512, 2) void gemm256(
    const unsigned short* __restrict__ A, long sA,
    const unsigned short* __restrict__ B, long sB,
    void* __restrict__ C, long sC,
    const float* __restrict__ bias,
    int K, int lda, int ldb, int ldc, float scale) {
  __shared__ unsigned short sm[2][2][256 * 64];   // [buf][A=0/B=1][256 rows x 64 cols]
  const int t    = threadIdx.x;
  const int lane = t & 63;
  const int wave = t >> 6;
  const int wm   = wave >> 2;          // 0..1  (M half)
  const int wn   = wave & 3;           // 0..3  (N quarter)
  const int fr   = lane & 15;
  const int g    = lane >> 4;          // k-group
  const int xr   = (fr & 7) << 4;      // read-side XOR (row&7)<<4, row%8 == fr%8

  const size_t row0 = (size_t)blockIdx.x * 256;
  const size_t col0 = (size_t)blockIdx.y * 256;
  const unsigned short* Ab = A + (size_t)blockIdx.z * (size_t)sA;
  const unsigned short* Bb = B + (size_t)blockIdx.z * (size_t)sB;

  // staging: thread t covers row (t>>3), 16B seg (t&7), source col pre-swizzled
  const int srow = t >> 3;                                       // 0..63 per chunk
  const int scol = ((((t & 7) << 4) ^ ((srow & 7) << 4)) >> 1);  // elements
  const unsigned short* gA = Ab + (row0 + srow) * (size_t)lda + scol;
  const unsigned short* gB = Bb + (col0 + srow) * (size_t)ldb + scol;

  // read-side element offsets
  const int arow = wm * 128 + fr;
  const int brow = wn * 64 + fr;
  const int c0 = (((g << 4)) ^ xr) >> 1;        // kk=0
  const int c1 = ((64 | (g << 4)) ^ xr) >> 1;   // kk=1

  f32x4 acc[8][4];
  const f32x4 z4 = {0.f, 0.f, 0.f, 0.f};
#pragma unroll
  for (int i = 0; i < 8; ++i)
#pragma unroll
    for (int j = 0; j < 4; ++j) acc[i][j] = z4;

  const int nt = K >> 6;   // K-tiles of 64

  // ---- prologue: T0 {A-lo,A-hi,B-lo,B-hi} -> buf0; T1 {B-lo,B-hi,A-lo} -> buf1
  stage_half(gA, lda, &sm[0][0][wave * 512]);
  stage_half(gA + 128 * (size_t)lda, lda, &sm[0][0][8192 + wave * 512]);
  stage_half(gB, ldb, &sm[0][1][wave * 512]);
  stage_half(gB + 128 * (size_t)ldb, ldb, &sm[0][1][8192 + wave * 512]);
  if (nt > 1) {
    stage_half(gB + 64, ldb, &sm[1][1][wave * 512]);
    stage_half(gB + 128 * (size_t)ldb + 64, ldb, &sm[1][1][8192 + wave * 512]);
    stage_half(gA + 64, lda, &sm[1][0][wave * 512]);
    asm volatile("s_waitcnt vmcnt(6)" ::: "memory");   // T0's 8 loads landed
  } else {
    asm volatile("s_waitcnt vmcnt(0)" ::: "memory");
  }
  BAR(); FENCE();

  bf16x8 a0[4][2], a1[4][2], b0[2][2], b1[2][2];

  for (int kt = 0; kt < nt; ++kt) {
    const int p = kt & 1;
    const unsigned short* As  = sm[p][0];
    const unsigned short* Bs2 = sm[p][1];

    // ---------------- P1: read A0-3 + B0-1 (12), stage T(kt+1).A-hi ----------------
#pragma unroll
    for (int mi = 0; mi < 4; ++mi) {
      a0[mi][0] = *(const bf16x8*)(As + (arow + mi * 16) * 64 + c0);
      a0[mi][1] = *(const bf16x8*)(As + (arow + mi * 16) * 64 + c1);
    }
#pragma unroll
    for (int ni = 0; ni < 2; ++ni) {
      b0[ni][0] = *(const bf16x8*)(Bs2 + (brow + ni * 16) * 64 + c0);
      b0[ni][1] = *(const bf16x8*)(Bs2 + (brow + ni * 16) * 64 + c1);
    }
    if (kt + 1 < nt)
      stage_half(gA + 128 * (size_t)lda + (size_t)(kt + 1) * 64, lda,
                 &sm[p ^ 1][0][8192 + wave * 512]);
    FENCE(); BAR(); FENCE();
    __builtin_amdgcn_s_setprio(1);
#pragma unroll
    for (int mi = 0; mi < 4; ++mi)
#pragma unroll
      for (int ni = 0; ni < 2; ++ni) {
        acc[mi][ni] = __builtin_amdgcn_mfma_f32_16x16x32_bf16(a0[mi][0], b0[ni][0], acc[mi][ni], 0, 0, 0);
        acc[mi][ni] = __builtin_amdgcn_mfma_f32_16x16x32_bf16(a0[mi][1], b0[ni][1], acc[mi][ni], 0, 0, 0);
      }
    __builtin_amdgcn_s_setprio(0);
    FENCE(); BAR(); FENCE();

    // ---------------- P2: read B2-3 (4) ----------------
#pragma unroll
    for (int ni = 0; ni < 2; ++ni) {
      b1[ni][0] = *(const bf16x8*)(Bs2 + (brow + (ni + 2) * 16) * 64 + c0);
      b1[ni][1] = *(const bf16x8*)(Bs2 + (brow + (ni + 2) * 16) * 64 + c1);
    }
    FENCE(); BAR(); FENCE();
    __builtin_amdgcn_s_setprio(1);
#pragma unroll
    for (int mi = 0; mi < 4; ++mi)
#pragma unroll
      for (int ni = 0; ni < 2; ++ni) {
        acc[mi][ni + 2] = __builtin_amdgcn_mfma_f32_16x16x32_bf16(a0[mi][0], b1[ni][0], acc[mi][ni + 2], 0, 0, 0);
        acc[mi][ni + 2] = __builtin_amdgcn_mfma_f32_16x16x32_bf16(a0[mi][1], b1[ni][1], acc[mi][ni + 2], 0, 0, 0);
      }
    __builtin_amdgcn_s_setprio(0);
    FENCE(); BAR(); FENCE();

    // ---------------- P3: read A4-7 (8), stage T(kt+2).B-lo (buf p free: B read done) --
#pragma unroll
    for (int mi = 0; mi < 4; ++mi) {
      a1[mi][0] = *(const bf16x8*)(As + (arow + (mi + 4) * 16) * 64 + c0);
      a1[mi][1] = *(const bf16x8*)(As + (arow + (mi + 4) * 16) * 64 + c1);
    }
    if (kt + 2 < nt)
      stage_half(gB + (size_t)(kt + 2) * 64, ldb, &sm[p][1][wave * 512]);
    FENCE(); BAR(); FENCE();
    __builtin_amdgcn_s_setprio(1);
#pragma unroll
    for (int mi = 0; mi < 4; ++mi)
#pragma unroll
      for (int ni = 0; ni < 2; ++ni) {
        acc[mi + 4][ni] = __builtin_amdgcn_mfma_f32_16x16x32_bf16(a1[mi][0], b0[ni][0], acc[mi + 4][ni], 0, 0, 0);
        acc[mi + 4][ni] = __builtin_amdgcn_mfma_f32_16x16x32_bf16(a1[mi][1], b0[ni][1], acc[mi + 4][ni], 0, 0, 0);
      }
    __builtin_amdgcn_s_setprio(0);
    FENCE(); BAR(); FENCE();

    // ---------------- P4: stage T(kt+2).{B-hi,A-lo}; counted vmcnt; MFMA q3 ----------
    if (kt + 2 < nt) {
      stage_half(gB + 128 * (size_t)ldb + (size_t)(kt + 2) * 64, ldb,
                 &sm[p][1][8192 + wave * 512]);
      stage_half(gA + (size_t)(kt + 2) * 64, lda, &sm[p][0][wave * 512]);
      // T(kt+1) fully landed: exactly 6 loads (P3:2 + P4:4) issued after its last one
      asm volatile("s_waitcnt vmcnt(6)" ::: "memory");
    } else {
      asm volatile("s_waitcnt vmcnt(0)" ::: "memory");
    }
    FENCE(); BAR(); FENCE();
    __builtin_amdgcn_s_setprio(1);
#pragma unroll
    for (int mi = 0; mi < 4; ++mi)
#pragma unroll
      for (int ni = 0; ni < 2; ++ni) {
        acc[mi + 4][ni + 2] = __builtin_amdgcn_mfma_f32_16x16x32_bf16(a1[mi][0], b1[ni][0], acc[mi + 4][ni + 2], 0, 0, 0);
        acc[mi + 4][ni + 2] = __builtin_amdgcn_mfma_f32_16x16x32_bf16(a1[mi][1], b1[ni][1], acc[mi + 4][ni + 2], 0, 0, 0);
      }
    __builtin_amdgcn_s_setprio(0);
    FENCE(); BAR(); FENCE();
  }

  // ---------------- epilogue: C/D layout col=lane&15, row=(lane>>4)*4+j ----------------
  const int rb = (lane >> 4) * 4;
  if constexpr (EPI == EPI_F32) {
    float* Co = (float*)C + (size_t)blockIdx.z * (size_t)sC;
#pragma unroll
    for (int mi = 0; mi < 8; ++mi) {
      size_t gr = row0 + wm * 128 + mi * 16 + rb;
#pragma unroll
      for (int ni = 0; ni < 4; ++ni) {
        size_t gc = col0 + wn * 64 + ni * 16 + fr;
#pragma unroll
        for (int j = 0; j < 4; ++j)
          Co[(gr + j) * (size_t)ldc + gc] = acc[mi][ni][j];
      }
    }
  } else if constexpr (EPI == EPI_SCALE) {
    unsigned short* Co = (unsigned short*)C + (size_t)blockIdx.z * (size_t)sC;
#pragma unroll
    for (int mi = 0; mi < 8; ++mi) {
      size_t gr = row0 + wm * 128 + mi * 16 + rb;
#pragma unroll
      for (int ni = 0; ni < 4; ++ni) {
        size_t gc = col0 + wn * 64 + ni * 16 + fr;
#pragma unroll
        for (int j = 0; j < 4; ++j)
          Co[(gr + j) * (size_t)ldc + gc] = f2bf(acc[mi][ni][j] * scale);
      }
    }
  } else if constexpr (EPI == EPI_QK) {
    unsigned short* Co = (unsigned short*)C;
#pragma unroll
    for (int ni = 0; ni < 4; ++ni) {
      size_t gc = col0 + wn * 64 + ni * 16 + fr;
      float bb = bias[gc];
#pragma unroll
      for (int mi = 0; mi < 8; ++mi) {
        size_t gr = row0 + wm * 128 + mi * 16 + rb;
#pragma unroll
        for (int j = 0; j < 4; ++j)
          Co[(gr + j) * (size_t)ldc + gc] = f2bf(acc[mi][ni][j] + bb);
      }
    }
  } else {  // EPI_VT: store transposed, C[gc][gr..gr+3] as ushort4
    unsigned short* Co = (unsigned short*)C;
#pragma unroll
    for (int ni = 0; ni < 4; ++ni) {
      size_t gc = col0 + wn * 64 + ni * 16 + fr;
      float bb = bias[gc];
#pragma unroll
      for (int mi = 0; mi < 8; ++mi) {
        size_t gr = row0 + wm * 128 + mi * 16 + rb;
        ushort4 pk;
        pk.x = f2bf(acc[mi][ni][0] + bb);
        pk.y = f2bf(acc[mi][ni][1] + bb);
        pk.z = f2bf(acc[mi][ni][2] + bb);
        pk.w = f2bf(acc[mi][ni][3] + bb);
        *(ushort4*)(Co + gc * (size_t)ldc + gr) = pk;
      }
    }
  }
}

// ---------------- row softmax in place on bf16 S rows of 4096 ----------------
__global__ __launch_bounds__(256) void softmax_rows(unsigned short* __restrict__ S, long sB) {
  const int t = threadIdx.x;
  unsigned short* row = S + (size_t)blockIdx.y * (size_t)sB + (size_t)blockIdx.x * SEQ;
  u16x8 a = *(const u16x8*)(row + t * 16);
  u16x8 b = *(const u16x8*)(row + t * 16 + 8);
  float v[16];
#pragma unroll
  for (int j = 0; j < 8; ++j) { v[j] = bf2f(a[j]); v[j + 8] = bf2f(b[j]); }
  float m = v[0];
#pragma unroll
  for (int j = 1; j < 16; ++j) m = fmaxf(m, v[j]);
  for (int off = 32; off > 0; off >>= 1) m = fmaxf(m, __shfl_xor(m, off));
  __shared__ float redm[4], reds[4];
  const int w = t >> 6;
  if ((t & 63) == 0) redm[w] = m;
  __syncthreads();
  m = fmaxf(fmaxf(redm[0], redm[1]), fmaxf(redm[2], redm[3]));
  float s = 0.f;
#pragma unroll
  for (int j = 0; j < 16; ++j) { v[j] = __expf(v[j] - m); s += v[j]; }
  for (int off = 32; off > 0; off >>= 1) s += __shfl_xor(s, off);
  if ((t & 63) == 0) reds[w] = s;
  __syncthreads();
  s = reds[0] + reds[1] + reds[2] + reds[3];
  float inv = 1.f / s;
#pragma unroll
  for (int j = 0; j < 8; ++j) { a[j] = f2bf(v[j] * inv); b[j] = f2bf(v[j + 8] * inv); }
  *(u16x8*)(row + t * 16) = a;
  *(u16x8*)(row + t * 16 + 8) = b;
}

extern "C" void kernel_launch(void* const* d_in, const int* in_sizes, int n_in,
                              void* d_out, int out_size, void* d_ws, size_t ws_size,
                              hipStream_t stream) {
  (void)in_sizes; (void)n_in; (void)out_size;
  const float* x  = (const float*)d_in[0];
  const float* Wq = (const float*)d_in[1];
  const float* bq = (const float*)d_in[2];
  const float* Wk = (const float*)d_in[3];
  const float* bk = (const float*)d_in[4];
  const float* Wv = (const float*)d_in[5];
  const float* bv = (const float*)d_in[6];
  float* out = (float*)d_out;

  const size_t EL   = (size_t)MTOT * DIM;
  const size_t SALL = (size_t)NB * SEQ * SEQ;
  const size_t WEL  = (size_t)3 * DIM * DIM;
  unsigned short* Q  = (unsigned short*)d_ws;
  unsigned short* Km = Q + EL;
  unsigned short* VT = Km + EL;                  // transposed: VT[e][b*SEQ+s]
  unsigned short* Sb = VT + EL;
  const bool allS = ws_size >= 2 * (3 * EL + SALL + WEL);
  unsigned short* WT = Sb + (allS ? SALL : EL);
  unsigned short* xb = Sb;                       // x_bf16 overlaps S (dead after proj)

  cvt_x<<<dim3(EL / 1024), dim3(256), 0, stream>>>(x, xb);
  transpose_w<<<dim3(32, 32), dim3(32, 8), 0, stream>>>(Wq, WT);
  transpose_w<<<dim3(32, 32), dim3(32, 8), 0, stream>>>(Wk, WT + DIM * DIM);
  transpose_w<<<dim3(32, 32), dim3(32, 8), 0, stream>>>(Wv, WT + 2 * DIM * DIM);

  dim3 gp(MTOT / 256, DIM / 256, 1);
  gemm256<EPI_QK><<<gp, 512, 0, stream>>>(xb, 0, WT, 0, Q, 0, bq, DIM, DIM, DIM, DIM, 1.f);
  gemm256<EPI_QK><<<gp, 512, 0, stream>>>(xb, 0, WT + DIM * DIM, 0, Km, 0, bk, DIM, DIM, DIM, DIM, 1.f);
  gemm256<EPI_VT><<<gp, 512, 0, stream>>>(xb, 0, WT + 2 * DIM * DIM, 0, VT, 0, bv, DIM, DIM, DIM, MTOT, 1.f);

  const float sc = 0.03125f;   // 1/sqrt(1024)
  if (allS) {
    gemm256<EPI_SCALE><<<dim3(SEQ / 256, SEQ / 256, NB), 512, 0, stream>>>(
        Q, (long)SEQ * DIM, Km, (long)SEQ * DIM, Sb, (long)SEQ * SEQ, nullptr,
        DIM, DIM, DIM, SEQ, sc);
    softmax_rows<<<dim3(SEQ, NB), 256, 0, stream>>>(Sb, (long)SEQ * SEQ);
    gemm256<EPI_F32><<<dim3(SEQ / 256, DIM / 256, NB), 512, 0, stream>>>(
        Sb, (long)SEQ * SEQ, VT, (long)SEQ, out, (long)SEQ * DIM, nullptr,
        SEQ, SEQ, MTOT, DIM, 1.f);
  } else {
    for (int b = 0; b < NB; ++b) {
      gemm256<EPI_SCALE><<<dim3(SEQ / 256, SEQ / 256, 1), 512, 0, stream>>>(
          Q + (size_t)b * SEQ * DIM, 0, Km + (size_t)b * SEQ * DIM, 0, Sb, 0, nullptr,
          DIM, DIM, DIM, SEQ, sc);
      softmax_rows<<<dim3(SEQ, 1), 256, 0, stream>>>(Sb, 0);
      gemm256<EPI_F32><<<dim3(SEQ / 256, DIM / 256, 1), 512, 0, stream>>>(
          Sb, 0, VT + (size_t)b * SEQ, 0, out + (size_t)b * SEQ * DIM, 0, nullptr,
          SEQ, SEQ, MTOT, DIM, 1.f);
    }
  }
}

// Round 4
// 419.723 us; speedup vs baseline: 1.5583x; 1.0708x over previous
//
#include <hip/hip_runtime.h>
#include <cstdint>

#define SEQ 4096
#define NB 4
#define DIM 1024
#define MTOT (NB * SEQ)   // 16384

using u16x8  = __attribute__((ext_vector_type(8))) unsigned short;
using bf16x8 = __attribute__((ext_vector_type(8))) __bf16;
using f32x4  = __attribute__((ext_vector_type(4))) float;

__device__ __forceinline__ unsigned short f2bf(float f) {
  unsigned u = __builtin_bit_cast(unsigned, f);
  u += 0x7fffu + ((u >> 16) & 1u);          // round-to-nearest-even
  return (unsigned short)(u >> 16);
}
__device__ __forceinline__ float bf2f(unsigned short h) {
  return __builtin_bit_cast(float, (unsigned)h << 16);
}

// async global->LDS, 16B/lane; LDS dest = wave-uniform base + lane*16
__device__ __forceinline__ void gload16(const unsigned short* g, unsigned short* l) {
  __builtin_amdgcn_global_load_lds(
      (const __attribute__((address_space(1))) unsigned int*)g,
      (__attribute__((address_space(3))) unsigned int*)l, 16, 0, 0);
}

__device__ __forceinline__ void stage_half(const unsigned short* gsrc, size_t ld,
                                           unsigned short* ldst) {
  gload16(gsrc, ldst);
  gload16(gsrc + 64 * ld, ldst + 64 * 64);
}

#define BAR()   __builtin_amdgcn_s_barrier()
#define FENCE() asm volatile("" ::: "memory")

// ---------------- convert x fp32 -> bf16 ----------------
__global__ __launch_bounds__(256) void cvt_x(const float* __restrict__ in,
                                             unsigned short* __restrict__ out) {
  size_t i = ((size_t)blockIdx.x * 256 + threadIdx.x) * 4;
  float4 v = *(const float4*)(in + i);
  ushort4 o;
  o.x = f2bf(v.x); o.y = f2bf(v.y); o.z = f2bf(v.z); o.w = f2bf(v.w);
  *(ushort4*)(out + i) = o;
}

// ---------------- W fp32 [1024][1024] -> WT bf16 [1024][1024] ----------------
__global__ __launch_bounds__(256) void transpose_w(const float* __restrict__ W,
                                                   unsigned short* __restrict__ WT) {
  __shared__ float tile[32][33];
  const int tx = threadIdx.x, ty = threadIdx.y;
  const int d0 = blockIdx.y * 32, e0 = blockIdx.x * 32;
#pragma unroll
  for (int j = 0; j < 32; j += 8)
    tile[ty + j][tx] = W[(size_t)(d0 + ty + j) * DIM + e0 + tx];
  __syncthreads();
#pragma unroll
  for (int j = 0; j < 32; j += 8)
    WT[(size_t)(e0 + ty + j) * DIM + d0 + tx] = f2bf(tile[tx][ty + j]);
}

// ============ 256x256 8-phase BT-GEMM: C[M,N] = A[M,K] * B^T (B stored [N,K]) ============
// 512 thr = 8 waves (2M x 4N); wave tile 128x64; BK=64; LDS 128KiB (2 K-tile bufs).
// Epilogues stage C through LDS (free after K-loop) for coalesced 16B stores.
enum { EPI_QK = 0, EPI_VT = 1, EPI_EXP = 2, EPI_F32DIV = 3 };

template <int EPI>
__global__ __launch_bounds__(512, 2) void gemm256(
    const unsigned short* __restrict__ A, long sA,
    const unsigned short* __restrict__ B, long sB,
    void* __restrict__ C, long sC,
    const float* __restrict__ bias,
    float* __restrict__ lsum,
    int K, int lda, int ldb, int ldc, float scale) {
  __shared__ unsigned short sm[2][2][256 * 64];   // 128 KiB
  const int t    = threadIdx.x;
  const int lane = t & 63;
  const int wave = t >> 6;
  const int wm   = wave >> 2;          // 0..1  (M half)
  const int wn   = wave & 3;           // 0..3  (N quarter)
  const int fr   = lane & 15;
  const int g    = lane >> 4;          // k-group
  const int xr   = (fr & 7) << 4;      // read-side XOR

  const size_t row0 = (size_t)blockIdx.x * 256;
  const size_t col0 = (size_t)blockIdx.y * 256;
  const unsigned short* Ab = A + (size_t)blockIdx.z * (size_t)sA;
  const unsigned short* Bb = B + (size_t)blockIdx.z * (size_t)sB;

  const int srow = t >> 3;
  const int scol = ((((t & 7) << 4) ^ ((srow & 7) << 4)) >> 1);
  const unsigned short* gA = Ab + (row0 + srow) * (size_t)lda + scol;
  const unsigned short* gB = Bb + (col0 + srow) * (size_t)ldb + scol;

  const int arow = wm * 128 + fr;
  const int brow = wn * 64 + fr;
  const int c0 = (((g << 4)) ^ xr) >> 1;
  const int c1 = ((64 | (g << 4)) ^ xr) >> 1;

  f32x4 acc[8][4];
  const f32x4 z4 = {0.f, 0.f, 0.f, 0.f};
#pragma unroll
  for (int i = 0; i < 8; ++i)
#pragma unroll
    for (int j = 0; j < 4; ++j) acc[i][j] = z4;

  const int nt = K >> 6;

  stage_half(gA, lda, &sm[0][0][wave * 512]);
  stage_half(gA + 128 * (size_t)lda, lda, &sm[0][0][8192 + wave * 512]);
  stage_half(gB, ldb, &sm[0][1][wave * 512]);
  stage_half(gB + 128 * (size_t)ldb, ldb, &sm[0][1][8192 + wave * 512]);
  if (nt > 1) {
    stage_half(gB + 64, ldb, &sm[1][1][wave * 512]);
    stage_half(gB + 128 * (size_t)ldb + 64, ldb, &sm[1][1][8192 + wave * 512]);
    stage_half(gA + 64, lda, &sm[1][0][wave * 512]);
    asm volatile("s_waitcnt vmcnt(6)" ::: "memory");
  } else {
    asm volatile("s_waitcnt vmcnt(0)" ::: "memory");
  }
  BAR(); FENCE();

  bf16x8 a0[4][2], a1[4][2], b0[2][2], b1[2][2];

  for (int kt = 0; kt < nt; ++kt) {
    const int p = kt & 1;
    const unsigned short* As  = sm[p][0];
    const unsigned short* Bs2 = sm[p][1];

    // P1: read A0-3 + B0-1 (12), stage T(kt+1).A-hi
#pragma unroll
    for (int mi = 0; mi < 4; ++mi) {
      a0[mi][0] = *(const bf16x8*)(As + (arow + mi * 16) * 64 + c0);
      a0[mi][1] = *(const bf16x8*)(As + (arow + mi * 16) * 64 + c1);
    }
#pragma unroll
    for (int ni = 0; ni < 2; ++ni) {
      b0[ni][0] = *(const bf16x8*)(Bs2 + (brow + ni * 16) * 64 + c0);
      b0[ni][1] = *(const bf16x8*)(Bs2 + (brow + ni * 16) * 64 + c1);
    }
    if (kt + 1 < nt)
      stage_half(gA + 128 * (size_t)lda + (size_t)(kt + 1) * 64, lda,
                 &sm[p ^ 1][0][8192 + wave * 512]);
    FENCE(); BAR(); FENCE();
    __builtin_amdgcn_s_setprio(1);
#pragma unroll
    for (int mi = 0; mi < 4; ++mi)
#pragma unroll
      for (int ni = 0; ni < 2; ++ni) {
        acc[mi][ni] = __builtin_amdgcn_mfma_f32_16x16x32_bf16(a0[mi][0], b0[ni][0], acc[mi][ni], 0, 0, 0);
        acc[mi][ni] = __builtin_amdgcn_mfma_f32_16x16x32_bf16(a0[mi][1], b0[ni][1], acc[mi][ni], 0, 0, 0);
      }
    __builtin_amdgcn_s_setprio(0);
    FENCE(); BAR(); FENCE();

    // P2: read B2-3 (4)
#pragma unroll
    for (int ni = 0; ni < 2; ++ni) {
      b1[ni][0] = *(const bf16x8*)(Bs2 + (brow + (ni + 2) * 16) * 64 + c0);
      b1[ni][1] = *(const bf16x8*)(Bs2 + (brow + (ni + 2) * 16) * 64 + c1);
    }
    FENCE(); BAR(); FENCE();
    __builtin_amdgcn_s_setprio(1);
#pragma unroll
    for (int mi = 0; mi < 4; ++mi)
#pragma unroll
      for (int ni = 0; ni < 2; ++ni) {
        acc[mi][ni + 2] = __builtin_amdgcn_mfma_f32_16x16x32_bf16(a0[mi][0], b1[ni][0], acc[mi][ni + 2], 0, 0, 0);
        acc[mi][ni + 2] = __builtin_amdgcn_mfma_f32_16x16x32_bf16(a0[mi][1], b1[ni][1], acc[mi][ni + 2], 0, 0, 0);
      }
    __builtin_amdgcn_s_setprio(0);
    FENCE(); BAR(); FENCE();

    // P3: read A4-7 (8), stage T(kt+2).B-lo
#pragma unroll
    for (int mi = 0; mi < 4; ++mi) {
      a1[mi][0] = *(const bf16x8*)(As + (arow + (mi + 4) * 16) * 64 + c0);
      a1[mi][1] = *(const bf16x8*)(As + (arow + (mi + 4) * 16) * 64 + c1);
    }
    if (kt + 2 < nt)
      stage_half(gB + (size_t)(kt + 2) * 64, ldb, &sm[p][1][wave * 512]);
    FENCE(); BAR(); FENCE();
    __builtin_amdgcn_s_setprio(1);
#pragma unroll
    for (int mi = 0; mi < 4; ++mi)
#pragma unroll
      for (int ni = 0; ni < 2; ++ni) {
        acc[mi + 4][ni] = __builtin_amdgcn_mfma_f32_16x16x32_bf16(a1[mi][0], b0[ni][0], acc[mi + 4][ni], 0, 0, 0);
        acc[mi + 4][ni] = __builtin_amdgcn_mfma_f32_16x16x32_bf16(a1[mi][1], b0[ni][1], acc[mi + 4][ni], 0, 0, 0);
      }
    __builtin_amdgcn_s_setprio(0);
    FENCE(); BAR(); FENCE();

    // P4: stage T(kt+2).{B-hi,A-lo}; counted vmcnt; MFMA q3
    if (kt + 2 < nt) {
      stage_half(gB + 128 * (size_t)ldb + (size_t)(kt + 2) * 64, ldb,
                 &sm[p][1][8192 + wave * 512]);
      stage_half(gA + (size_t)(kt + 2) * 64, lda, &sm[p][0][wave * 512]);
      asm volatile("s_waitcnt vmcnt(6)" ::: "memory");
    } else {
      asm volatile("s_waitcnt vmcnt(0)" ::: "memory");
    }
    FENCE(); BAR(); FENCE();
    __builtin_amdgcn_s_setprio(1);
#pragma unroll
    for (int mi = 0; mi < 4; ++mi)
#pragma unroll
      for (int ni = 0; ni < 2; ++ni) {
        acc[mi + 4][ni + 2] = __builtin_amdgcn_mfma_f32_16x16x32_bf16(a1[mi][0], b1[ni][0], acc[mi + 4][ni + 2], 0, 0, 0);
        acc[mi + 4][ni + 2] = __builtin_amdgcn_mfma_f32_16x16x32_bf16(a1[mi][1], b1[ni][1], acc[mi + 4][ni + 2], 0, 0, 0);
      }
    __builtin_amdgcn_s_setprio(0);
    FENCE(); BAR(); FENCE();
  }

  // ===================== LDS-staged coalesced epilogues =====================
  // Frag layout: col = lane&15 (fr), row = (lane>>4)*4 + j. LDS free after loop.
  char* Lb = (char*)&sm[0][0][0];
  const int rb = (lane >> 4) * 4;

  if constexpr (EPI == EPI_QK || EPI == EPI_EXP) {
    // write phase: bf16 row-major [r][c], byte = r*512 + ((c*2)^((r&7)<<4))
    float bb[4];
    if constexpr (EPI == EPI_QK) {
#pragma unroll
      for (int ni = 0; ni < 4; ++ni) bb[ni] = bias[col0 + wn * 64 + ni * 16 + fr];
    }
#pragma unroll
    for (int mi = 0; mi < 8; ++mi) {
      const int r0 = wm * 128 + mi * 16 + rb;
#pragma unroll
      for (int ni = 0; ni < 4; ++ni) {
        const int c = wn * 64 + ni * 16 + fr;
#pragma unroll
        for (int j = 0; j < 4; ++j) {
          const int r = r0 + j;
          float v = acc[mi][ni][j];
          if constexpr (EPI == EPI_EXP) v = __expf(v * scale);
          else                          v = v + bb[ni];
          *(unsigned short*)(Lb + r * 512 + ((c * 2) ^ ((r & 7) << 4))) = f2bf(v);
        }
      }
    }
    __syncthreads();
    // readout: lanes 0-31 cover a full 512B row run
    unsigned short* Co = (unsigned short*)C +
        (EPI == EPI_EXP ? (size_t)blockIdx.z * (size_t)sC : (size_t)0);
#pragma unroll 4
    for (int i = 0; i < 16; ++i) {
      const int G = i * 512 + t;
      const int r = G >> 5, c16 = G & 31;
      u16x8 v = *(const u16x8*)(Lb + r * 512 + ((c16 * 16) ^ ((r & 7) << 4)));
      *(u16x8*)(Co + (row0 + r) * (size_t)ldc + col0 + c16 * 8) = v;
    }
    if constexpr (EPI == EPI_EXP) {
      // row-sum pass: 2 threads/row, 16 granules each (32 granules = 256 cols)
      const int r = t >> 1;
      float s = 0.f;
#pragma unroll
      for (int k = 0; k < 16; ++k) {
        const int c16 = (t & 1) * 16 + k;
        u16x8 v = *(const u16x8*)(Lb + r * 512 + ((c16 * 16) ^ ((r & 7) << 4)));
#pragma unroll
        for (int q = 0; q < 8; ++q) s += bf2f(v[q]);
      }
      atomicAdd(&lsum[(size_t)blockIdx.z * SEQ + row0 + r], s);
    }
  } else if constexpr (EPI == EPI_VT) {
    // col-major [c][r] bf16, frag j-rows pack to one 8B write
#pragma unroll
    for (int ni = 0; ni < 4; ++ni) {
      const int c = wn * 64 + ni * 16 + fr;
      const float bb = bias[col0 + c];
#pragma unroll
      for (int mi = 0; mi < 8; ++mi) {
        const int r0 = wm * 128 + mi * 16 + rb;
        ushort4 pk;
        pk.x = f2bf(acc[mi][ni][0] + bb);
        pk.y = f2bf(acc[mi][ni][1] + bb);
        pk.z = f2bf(acc[mi][ni][2] + bb);
        pk.w = f2bf(acc[mi][ni][3] + bb);
        *(ushort4*)(Lb + c * 512 + ((r0 * 2) ^ ((c & 7) << 4))) = pk;
      }
    }
    __syncthreads();
    unsigned short* Co = (unsigned short*)C;
#pragma unroll 4
    for (int i = 0; i < 16; ++i) {
      const int G = i * 512 + t;
      const int e = G >> 5, m16 = G & 31;
      u16x8 v = *(const u16x8*)(Lb + e * 512 + ((m16 * 16) ^ ((e & 7) << 4)));
      *(u16x8*)(Co + (col0 + e) * (size_t)ldc + row0 + m16 * 8) = v;
    }
  } else {  // EPI_F32DIV: fp32 out / lsum[row], two 128-row halves through LDS
    float* Co = (float*)C + (size_t)blockIdx.z * (size_t)sC;
#pragma unroll
    for (int h = 0; h < 2; ++h) {
      if (h) __syncthreads();          // half-0 readout done before overwrite
      if (wm == h) {
#pragma unroll
        for (int mi = 0; mi < 8; ++mi) {
          const int r0 = mi * 16 + rb;   // local 0..127
#pragma unroll
          for (int ni = 0; ni < 4; ++ni) {
            const int c = wn * 64 + ni * 16 + fr;
#pragma unroll
            for (int j = 0; j < 4; ++j) {
              const int r = r0 + j;
              *(float*)(Lb + r * 1024 + ((c * 4) ^ ((r & 7) << 4))) = acc[mi][ni][j];
            }
          }
        }
      }
      __syncthreads();
#pragma unroll 4
      for (int i = 0; i < 16; ++i) {
        const int G = i * 512 + t;
        const int r = G >> 6, c4 = G & 63;
        f32x4 v = *(const f32x4*)(Lb + r * 1024 + ((c4 * 16) ^ ((r & 7) << 4)));
        const size_t grow = row0 + h * 128 + r;
        const float inv = 1.0f / lsum[(size_t)blockIdx.z * SEQ + grow];
        v *= inv;
        *(f32x4*)(Co + grow * (size_t)ldc + col0 + c4 * 4) = v;
      }
    }
  }
}

extern "C" void kernel_launch(void* const* d_in, const int* in_sizes, int n_in,
                              void* d_out, int out_size, void* d_ws, size_t ws_size,
                              hipStream_t stream) {
  (void)in_sizes; (void)n_in; (void)out_size;
  const float* x  = (const float*)d_in[0];
  const float* Wq = (const float*)d_in[1];
  const float* bq = (const float*)d_in[2];
  const float* Wk = (const float*)d_in[3];
  const float* bk = (const float*)d_in[4];
  const float* Wv = (const float*)d_in[5];
  const float* bv = (const float*)d_in[6];
  float* out = (float*)d_out;

  const size_t EL   = (size_t)MTOT * DIM;
  const size_t SALL = (size_t)NB * SEQ * SEQ;
  unsigned short* Q  = (unsigned short*)d_ws;
  unsigned short* Km = Q + EL;
  unsigned short* VT = Km + EL;                  // transposed: VT[e][b*SEQ+s]
  unsigned short* Sb = VT + EL;                  // E = exp(S/32), unnormalized
  unsigned short* WT = Sb + SALL;
  float*          l  = (float*)(WT + (size_t)3 * DIM * DIM);   // [MTOT] row sums
  unsigned short* xb = Sb;                       // x_bf16 overlaps E (dead after proj)

  hipMemsetAsync(l, 0, MTOT * sizeof(float), stream);

  cvt_x<<<dim3(EL / 1024), dim3(256), 0, stream>>>(x, xb);
  transpose_w<<<dim3(32, 32), dim3(32, 8), 0, stream>>>(Wq, WT);
  transpose_w<<<dim3(32, 32), dim3(32, 8), 0, stream>>>(Wk, WT + DIM * DIM);
  transpose_w<<<dim3(32, 32), dim3(32, 8), 0, stream>>>(Wv, WT + 2 * DIM * DIM);

  dim3 gp(MTOT / 256, DIM / 256, 1);
  gemm256<EPI_QK><<<gp, 512, 0, stream>>>(xb, 0, WT, 0, Q, 0, bq, nullptr,
                                          DIM, DIM, DIM, DIM, 1.f);
  gemm256<EPI_QK><<<gp, 512, 0, stream>>>(xb, 0, WT + DIM * DIM, 0, Km, 0, bk, nullptr,
                                          DIM, DIM, DIM, DIM, 1.f);
  gemm256<EPI_VT><<<gp, 512, 0, stream>>>(xb, 0, WT + 2 * DIM * DIM, 0, VT, 0, bv, nullptr,
                                          DIM, DIM, DIM, MTOT, 1.f);

  const float sc = 0.03125f;   // 1/sqrt(1024)
  // E = exp(QK^T/32) (bf16) + row sums l (atomics)
  gemm256<EPI_EXP><<<dim3(SEQ / 256, SEQ / 256, NB), 512, 0, stream>>>(
      Q, (long)SEQ * DIM, Km, (long)SEQ * DIM, Sb, (long)SEQ * SEQ, nullptr, l,
      DIM, DIM, DIM, SEQ, sc);
  // O = (E · V) / l  (fp32 out)
  gemm256<EPI_F32DIV><<<dim3(SEQ / 256, DIM / 256, NB), 512, 0, stream>>>(
      Sb, (long)SEQ * SEQ, VT, (long)SEQ, out, (long)SEQ * DIM, nullptr, l,
      SEQ, SEQ, MTOT, DIM, 1.f);
}

// Round 5
// 412.939 us; speedup vs baseline: 1.5839x; 1.0164x over previous
//
#include <hip/hip_runtime.h>
#include <cstdint>

#define SEQ 4096
#define NB 4
#define DIM 1024
#define MTOT (NB * SEQ)   // 16384
constexpr size_t EL = (size_t)MTOT * DIM;

using u16x8  = __attribute__((ext_vector_type(8))) unsigned short;
using bf16x8 = __attribute__((ext_vector_type(8))) __bf16;
using f32x4  = __attribute__((ext_vector_type(4))) float;

__device__ __forceinline__ unsigned short f2bf(float f) {
  unsigned u = __builtin_bit_cast(unsigned, f);
  u += 0x7fffu + ((u >> 16) & 1u);          // round-to-nearest-even
  return (unsigned short)(u >> 16);
}
__device__ __forceinline__ float bf2f(unsigned short h) {
  return __builtin_bit_cast(float, (unsigned)h << 16);
}

__device__ __forceinline__ void gload16(const unsigned short* g, unsigned short* l) {
  __builtin_amdgcn_global_load_lds(
      (const __attribute__((address_space(1))) unsigned int*)g,
      (__attribute__((address_space(3))) unsigned int*)l, 16, 0, 0);
}
__device__ __forceinline__ void stage_half(const unsigned short* gsrc, size_t ld,
                                           unsigned short* ldst) {
  gload16(gsrc, ldst);
  gload16(gsrc + 64 * ld, ldst + 64 * 64);
}

#define BAR()   __builtin_amdgcn_s_barrier()
#define FENCE() asm volatile("" ::: "memory")

// ---------------- convert x fp32 -> bf16 ----------------
__global__ __launch_bounds__(256) void cvt_x(const float* __restrict__ in,
                                             unsigned short* __restrict__ out) {
  size_t i = ((size_t)blockIdx.x * 256 + threadIdx.x) * 4;
  float4 v = *(const float4*)(in + i);
  ushort4 o;
  o.x = f2bf(v.x); o.y = f2bf(v.y); o.z = f2bf(v.z); o.w = f2bf(v.w);
  *(ushort4*)(out + i) = o;
}

// ---------------- W fp32 [1024][1024] -> WT bf16 [1024][1024] ----------------
__global__ __launch_bounds__(256) void transpose_w(const float* __restrict__ W,
                                                   unsigned short* __restrict__ WT) {
  __shared__ float tile[32][33];
  const int tx = threadIdx.x, ty = threadIdx.y;
  const int d0 = blockIdx.y * 32, e0 = blockIdx.x * 32;
#pragma unroll
  for (int j = 0; j < 32; j += 8)
    tile[ty + j][tx] = W[(size_t)(d0 + ty + j) * DIM + e0 + tx];
  __syncthreads();
#pragma unroll
  for (int j = 0; j < 32; j += 8)
    WT[(size_t)(e0 + ty + j) * DIM + d0 + tx] = f2bf(tile[tx][ty + j]);
}

// ---------------- concat biases [bq|bk|bv] -> bcat[3072] ----------------
__global__ __launch_bounds__(256) void cat_bias(const float* __restrict__ bq,
                                                const float* __restrict__ bk,
                                                const float* __restrict__ bv,
                                                float* __restrict__ bcat) {
  int i = blockIdx.x * 256 + threadIdx.x;   // grid 12
  float v = (i < 1024) ? bq[i] : (i < 2048) ? bk[i - 1024] : bv[i - 2048];
  bcat[i] = v;
}

// ============ 256x256 8-phase BT-GEMM body: C[M,N] = A[M,K] * B^T ============
// 512 thr = 8 waves (2M x 4N); wave tile 128x64; BK=64; LDS 128KiB (2 K-tile bufs).
enum { EPI_QKV = 0, EPI_EXP = 1, EPI_PV = 2 };

template <int EPI>
__device__ __forceinline__ void gemm_body(
    const unsigned short* __restrict__ A, const unsigned short* __restrict__ B,
    void* __restrict__ C, const float* __restrict__ bias, float* __restrict__ lsum,
    int K, int lda, int ldb, int ldc, float scale,
    int row0, int col0, int bz, long sA, long sB, long sC) {
  __shared__ unsigned short sm[2][2][256 * 64];   // 128 KiB
  const int t    = threadIdx.x;
  const int lane = t & 63;
  const int wave = t >> 6;
  const int wm   = wave >> 2;          // 0..1  (M half)
  const int wn   = wave & 3;           // 0..3  (N quarter)
  const int fr   = lane & 15;
  const int g    = lane >> 4;          // k-group
  const int xr   = (fr & 7) << 4;      // read-side XOR

  const unsigned short* Ab = A + (size_t)bz * (size_t)sA;
  const unsigned short* Bb = B + (size_t)bz * (size_t)sB;

  const int srow = t >> 3;
  const int scol = ((((t & 7) << 4) ^ ((srow & 7) << 4)) >> 1);
  const unsigned short* gA = Ab + (size_t)(row0 + srow) * (size_t)lda + scol;
  const unsigned short* gB = Bb + (size_t)(col0 + srow) * (size_t)ldb + scol;

  const int arow = wm * 128 + fr;
  const int brow = wn * 64 + fr;
  const int c0 = (((g << 4)) ^ xr) >> 1;
  const int c1 = ((64 | (g << 4)) ^ xr) >> 1;

  f32x4 acc[8][4];
  const f32x4 z4 = {0.f, 0.f, 0.f, 0.f};
#pragma unroll
  for (int i = 0; i < 8; ++i)
#pragma unroll
    for (int j = 0; j < 4; ++j) acc[i][j] = z4;

  const int nt = K >> 6;

  stage_half(gA, lda, &sm[0][0][wave * 512]);
  stage_half(gA + 128 * (size_t)lda, lda, &sm[0][0][8192 + wave * 512]);
  stage_half(gB, ldb, &sm[0][1][wave * 512]);
  stage_half(gB + 128 * (size_t)ldb, ldb, &sm[0][1][8192 + wave * 512]);
  if (nt > 1) {
    stage_half(gB + 64, ldb, &sm[1][1][wave * 512]);
    stage_half(gB + 128 * (size_t)ldb + 64, ldb, &sm[1][1][8192 + wave * 512]);
    stage_half(gA + 64, lda, &sm[1][0][wave * 512]);
    asm volatile("s_waitcnt vmcnt(6)" ::: "memory");
  } else {
    asm volatile("s_waitcnt vmcnt(0)" ::: "memory");
  }
  BAR(); FENCE();

  bf16x8 a0[4][2], a1[4][2], b0[2][2], b1[2][2];

  for (int kt = 0; kt < nt; ++kt) {
    const int p = kt & 1;
    const unsigned short* As  = sm[p][0];
    const unsigned short* Bs2 = sm[p][1];

    // P1: read A0-3 + B0-1 (12), stage T(kt+1).A-hi
#pragma unroll
    for (int mi = 0; mi < 4; ++mi) {
      a0[mi][0] = *(const bf16x8*)(As + (arow + mi * 16) * 64 + c0);
      a0[mi][1] = *(const bf16x8*)(As + (arow + mi * 16) * 64 + c1);
    }
#pragma unroll
    for (int ni = 0; ni < 2; ++ni) {
      b0[ni][0] = *(const bf16x8*)(Bs2 + (brow + ni * 16) * 64 + c0);
      b0[ni][1] = *(const bf16x8*)(Bs2 + (brow + ni * 16) * 64 + c1);
    }
    if (kt + 1 < nt)
      stage_half(gA + 128 * (size_t)lda + (size_t)(kt + 1) * 64, lda,
                 &sm[p ^ 1][0][8192 + wave * 512]);
    FENCE(); BAR(); FENCE();
    __builtin_amdgcn_s_setprio(1);
#pragma unroll
    for (int mi = 0; mi < 4; ++mi)
#pragma unroll
      for (int ni = 0; ni < 2; ++ni) {
        acc[mi][ni] = __builtin_amdgcn_mfma_f32_16x16x32_bf16(a0[mi][0], b0[ni][0], acc[mi][ni], 0, 0, 0);
        acc[mi][ni] = __builtin_amdgcn_mfma_f32_16x16x32_bf16(a0[mi][1], b0[ni][1], acc[mi][ni], 0, 0, 0);
      }
    __builtin_amdgcn_s_setprio(0);
    FENCE(); BAR(); FENCE();

    // P2: read B2-3 (4)
#pragma unroll
    for (int ni = 0; ni < 2; ++ni) {
      b1[ni][0] = *(const bf16x8*)(Bs2 + (brow + (ni + 2) * 16) * 64 + c0);
      b1[ni][1] = *(const bf16x8*)(Bs2 + (brow + (ni + 2) * 16) * 64 + c1);
    }
    FENCE(); BAR(); FENCE();
    __builtin_amdgcn_s_setprio(1);
#pragma unroll
    for (int mi = 0; mi < 4; ++mi)
#pragma unroll
      for (int ni = 0; ni < 2; ++ni) {
        acc[mi][ni + 2] = __builtin_amdgcn_mfma_f32_16x16x32_bf16(a0[mi][0], b1[ni][0], acc[mi][ni + 2], 0, 0, 0);
        acc[mi][ni + 2] = __builtin_amdgcn_mfma_f32_16x16x32_bf16(a0[mi][1], b1[ni][1], acc[mi][ni + 2], 0, 0, 0);
      }
    __builtin_amdgcn_s_setprio(0);
    FENCE(); BAR(); FENCE();

    // P3: read A4-7 (8), stage T(kt+2).B-lo
#pragma unroll
    for (int mi = 0; mi < 4; ++mi) {
      a1[mi][0] = *(const bf16x8*)(As + (arow + (mi + 4) * 16) * 64 + c0);
      a1[mi][1] = *(const bf16x8*)(As + (arow + (mi + 4) * 16) * 64 + c1);
    }
    if (kt + 2 < nt)
      stage_half(gB + (size_t)(kt + 2) * 64, ldb, &sm[p][1][wave * 512]);
    FENCE(); BAR(); FENCE();
    __builtin_amdgcn_s_setprio(1);
#pragma unroll
    for (int mi = 0; mi < 4; ++mi)
#pragma unroll
      for (int ni = 0; ni < 2; ++ni) {
        acc[mi + 4][ni] = __builtin_amdgcn_mfma_f32_16x16x32_bf16(a1[mi][0], b0[ni][0], acc[mi + 4][ni], 0, 0, 0);
        acc[mi + 4][ni] = __builtin_amdgcn_mfma_f32_16x16x32_bf16(a1[mi][1], b0[ni][1], acc[mi + 4][ni], 0, 0, 0);
      }
    __builtin_amdgcn_s_setprio(0);
    FENCE(); BAR(); FENCE();

    // P4: stage T(kt+2).{B-hi,A-lo}; counted vmcnt; MFMA q3
    if (kt + 2 < nt) {
      stage_half(gB + 128 * (size_t)ldb + (size_t)(kt + 2) * 64, ldb,
                 &sm[p][1][8192 + wave * 512]);
      stage_half(gA + (size_t)(kt + 2) * 64, lda, &sm[p][0][wave * 512]);
      asm volatile("s_waitcnt vmcnt(6)" ::: "memory");
    } else {
      asm volatile("s_waitcnt vmcnt(0)" ::: "memory");
    }
    FENCE(); BAR(); FENCE();
    __builtin_amdgcn_s_setprio(1);
#pragma unroll
    for (int mi = 0; mi < 4; ++mi)
#pragma unroll
      for (int ni = 0; ni < 2; ++ni) {
        acc[mi + 4][ni + 2] = __builtin_amdgcn_mfma_f32_16x16x32_bf16(a1[mi][0], b1[ni][0], acc[mi + 4][ni + 2], 0, 0, 0);
        acc[mi + 4][ni + 2] = __builtin_amdgcn_mfma_f32_16x16x32_bf16(a1[mi][1], b1[ni][1], acc[mi + 4][ni + 2], 0, 0, 0);
      }
    __builtin_amdgcn_s_setprio(0);
    FENCE(); BAR(); FENCE();
  }

  // ===================== LDS-staged coalesced epilogues =====================
  char* Lb = (char*)&sm[0][0][0];
  const int rb = (lane >> 4) * 4;

  if constexpr (EPI == EPI_QKV) {
    const int which = col0 >> 10;            // 0=Q 1=K 2=V
    const int lc0   = col0 & 1023;
    unsigned short* Co = (unsigned short*)C + (size_t)which * EL;
    if (which < 2) {
      float bb[4];
#pragma unroll
      for (int ni = 0; ni < 4; ++ni) bb[ni] = bias[col0 + wn * 64 + ni * 16 + fr];
#pragma unroll
      for (int mi = 0; mi < 8; ++mi) {
        const int r0 = wm * 128 + mi * 16 + rb;
#pragma unroll
        for (int ni = 0; ni < 4; ++ni) {
          const int c = wn * 64 + ni * 16 + fr;
#pragma unroll
          for (int j = 0; j < 4; ++j) {
            const int r = r0 + j;
            *(unsigned short*)(Lb + r * 512 + ((c * 2) ^ ((r & 7) << 4))) =
                f2bf(acc[mi][ni][j] + bb[ni]);
          }
        }
      }
      __syncthreads();
#pragma unroll 4
      for (int i = 0; i < 16; ++i) {
        const int G = i * 512 + t;
        const int r = G >> 5, c16 = G & 31;
        u16x8 v = *(const u16x8*)(Lb + r * 512 + ((c16 * 16) ^ ((r & 7) << 4)));
        *(u16x8*)(Co + (size_t)(row0 + r) * DIM + lc0 + c16 * 8) = v;
      }
    } else {
      // V: store transposed through col-major LDS tile
#pragma unroll
      for (int ni = 0; ni < 4; ++ni) {
        const int c = wn * 64 + ni * 16 + fr;
        const float bb = bias[col0 + c];
#pragma unroll
        for (int mi = 0; mi < 8; ++mi) {
          const int r0 = wm * 128 + mi * 16 + rb;
          ushort4 pk;
          pk.x = f2bf(acc[mi][ni][0] + bb);
          pk.y = f2bf(acc[mi][ni][1] + bb);
          pk.z = f2bf(acc[mi][ni][2] + bb);
          pk.w = f2bf(acc[mi][ni][3] + bb);
          *(ushort4*)(Lb + c * 512 + ((r0 * 2) ^ ((c & 7) << 4))) = pk;
        }
      }
      __syncthreads();
#pragma unroll 4
      for (int i = 0; i < 16; ++i) {
        const int G = i * 512 + t;
        const int e = G >> 5, m16 = G & 31;
        u16x8 v = *(const u16x8*)(Lb + e * 512 + ((m16 * 16) ^ ((e & 7) << 4)));
        *(u16x8*)(Co + (size_t)(lc0 + e) * MTOT + row0 + m16 * 8) = v;
      }
    }
  } else if constexpr (EPI == EPI_EXP) {
    // E = exp2(acc*scale) bf16, + row sums via LDS re-read
#pragma unroll
    for (int mi = 0; mi < 8; ++mi) {
      const int r0 = wm * 128 + mi * 16 + rb;
#pragma unroll
      for (int ni = 0; ni < 4; ++ni) {
        const int c = wn * 64 + ni * 16 + fr;
#pragma unroll
        for (int j = 0; j < 4; ++j) {
          const int r = r0 + j;
          *(unsigned short*)(Lb + r * 512 + ((c * 2) ^ ((r & 7) << 4))) =
              f2bf(exp2f(acc[mi][ni][j] * scale));
        }
      }
    }
    __syncthreads();
    unsigned short* Co = (unsigned short*)C + (size_t)bz * (size_t)sC;
#pragma unroll 4
    for (int i = 0; i < 16; ++i) {
      const int G = i * 512 + t;
      const int r = G >> 5, c16 = G & 31;
      u16x8 v = *(const u16x8*)(Lb + r * 512 + ((c16 * 16) ^ ((r & 7) << 4)));
      *(u16x8*)(Co + (size_t)(row0 + r) * (size_t)ldc + col0 + c16 * 8) = v;
    }
    {   // row-sum: 2 threads/row, 16 granules each (all 256 cols)
      const int r = t >> 1;
      float s = 0.f;
#pragma unroll
      for (int k = 0; k < 16; ++k) {
        const int c16 = (t & 1) * 16 + k;
        u16x8 v = *(const u16x8*)(Lb + r * 512 + ((c16 * 16) ^ ((r & 7) << 4)));
#pragma unroll
        for (int q = 0; q < 8; ++q) s += bf2f(v[q]);
      }
      atomicAdd(&lsum[(size_t)bz * SEQ + row0 + r], s);
    }
  } else {  // EPI_PV: fp32 out / lsum[row], two 128-row halves through LDS
    float* Co = (float*)C + (size_t)bz * (size_t)sC;
#pragma unroll
    for (int h = 0; h < 2; ++h) {
      if (h) __syncthreads();
      if (wm == h) {
#pragma unroll
        for (int mi = 0; mi < 8; ++mi) {
          const int r0 = mi * 16 + rb;
#pragma unroll
          for (int ni = 0; ni < 4; ++ni) {
            const int c = wn * 64 + ni * 16 + fr;
#pragma unroll
            for (int j = 0; j < 4; ++j) {
              const int r = r0 + j;
              *(float*)(Lb + r * 1024 + ((c * 4) ^ ((r & 7) << 4))) = acc[mi][ni][j];
            }
          }
        }
      }
      __syncthreads();
#pragma unroll 4
      for (int i = 0; i < 16; ++i) {
        const int G = i * 512 + t;
        const int r = G >> 6, c4 = G & 63;
        f32x4 v = *(const f32x4*)(Lb + r * 1024 + ((c4 * 16) ^ ((r & 7) << 4)));
        const size_t grow = (size_t)row0 + h * 128 + r;
        const float inv = 1.0f / lsum[(size_t)bz * SEQ + grow];
        v *= inv;
        *(f32x4*)(Co + grow * (size_t)ldc + col0 + c4 * 4) = v;
      }
    }
  }
}

// ---------------- named wrappers (distinct rocprof attribution) ----------------
__global__ __launch_bounds__(512, 2) void gemm_qkv(
    const unsigned short* __restrict__ A, const unsigned short* __restrict__ B,
    unsigned short* __restrict__ C, const float* __restrict__ bcat) {
  gemm_body<EPI_QKV>(A, B, C, bcat, nullptr, DIM, DIM, DIM, DIM, 1.f,
                     (int)blockIdx.x * 256, (int)blockIdx.y * 256, 0, 0, 0, 0);
}

__global__ __launch_bounds__(512, 2) void gemm_exp(
    const unsigned short* __restrict__ A, const unsigned short* __restrict__ B,
    unsigned short* __restrict__ C, float* __restrict__ lsum) {
  // E = exp2(S * log2e/32); scale folds 1/sqrt(1024) and log2(e)
  gemm_body<EPI_EXP>(A, B, C, nullptr, lsum, DIM, DIM, DIM, SEQ, 0.04508422f,
                     (int)blockIdx.x * 256, (int)blockIdx.y * 256, (int)blockIdx.z,
                     (long)SEQ * DIM, (long)SEQ * DIM, (long)SEQ * SEQ);
}

__global__ __launch_bounds__(512, 2) void gemm_pv(
    const unsigned short* __restrict__ A, const unsigned short* __restrict__ B,
    float* __restrict__ C, float* __restrict__ lsum) {
  // grid (4,16,NB) flat-swizzled so each XCD gets 8 row-tiles x 4 col-tiles
  const int flat = (int)blockIdx.x +
                   (int)gridDim.x * ((int)blockIdx.y + (int)gridDim.y * (int)blockIdx.z);
  const int nf  = (flat & 7) * 32 + (flat >> 3);   // 256 = 8 XCD x 32, bijective
  const int b   = nf >> 6;
  const int rc  = nf & 63;
  const int row = rc >> 2, col = rc & 3;
  gemm_body<EPI_PV>(A, B, C, nullptr, lsum, SEQ, SEQ, MTOT, DIM, 1.f,
                    row * 256, col * 256, b,
                    (long)SEQ * SEQ, (long)SEQ, (long)SEQ * DIM);
}

extern "C" void kernel_launch(void* const* d_in, const int* in_sizes, int n_in,
                              void* d_out, int out_size, void* d_ws, size_t ws_size,
                              hipStream_t stream) {
  (void)in_sizes; (void)n_in; (void)out_size; (void)ws_size;
  const float* x  = (const float*)d_in[0];
  const float* Wq = (const float*)d_in[1];
  const float* bq = (const float*)d_in[2];
  const float* Wk = (const float*)d_in[3];
  const float* bk = (const float*)d_in[4];
  const float* Wv = (const float*)d_in[5];
  const float* bv = (const float*)d_in[6];
  float* out = (float*)d_out;

  const size_t SALL = (size_t)NB * SEQ * SEQ;
  unsigned short* Q  = (unsigned short*)d_ws;
  unsigned short* Km = Q + EL;
  unsigned short* VT = Km + EL;                  // transposed: VT[e][b*SEQ+s]
  unsigned short* Sb = VT + EL;                  // E = exp(S/32), unnormalized
  unsigned short* WT = Sb + SALL;                // [3072][1024] = WqT|WkT|WvT
  float*          l  = (float*)(WT + (size_t)3 * DIM * DIM);   // [MTOT] row sums
  float*          bc = l + MTOT;                 // bcat[3072]
  unsigned short* xb = Sb;                       // x_bf16 overlaps E (dead after proj)

  hipMemsetAsync(l, 0, MTOT * sizeof(float), stream);

  cvt_x<<<dim3(EL / 1024), dim3(256), 0, stream>>>(x, xb);
  transpose_w<<<dim3(32, 32), dim3(32, 8), 0, stream>>>(Wq, WT);
  transpose_w<<<dim3(32, 32), dim3(32, 8), 0, stream>>>(Wk, WT + DIM * DIM);
  transpose_w<<<dim3(32, 32), dim3(32, 8), 0, stream>>>(Wv, WT + 2 * DIM * DIM);
  cat_bias<<<dim3(12), dim3(256), 0, stream>>>(bq, bk, bv, bc);

  // fused QKV projection: [16384,1024] x [3072,1024]^T, epilogue routes Q/K/VT
  gemm_qkv<<<dim3(MTOT / 256, 3 * DIM / 256), 512, 0, stream>>>(xb, WT, Q, bc);

  // E = exp(QK^T/32) (bf16) + row sums l (atomics)
  gemm_exp<<<dim3(SEQ / 256, SEQ / 256, NB), 512, 0, stream>>>(Q, Km, Sb, l);

  // O = (E · V) / l  (fp32 out), XCD-swizzled grid
  gemm_pv<<<dim3(DIM / 256, SEQ / 256, NB), 512, 0, stream>>>(Sb, VT, out, l);
}

// Round 6
// 401.918 us; speedup vs baseline: 1.6273x; 1.0274x over previous
//
#include <hip/hip_runtime.h>
#include <hip/hip_bf16.h>
#include <cstdint>

#define SEQ 4096
#define NB 4
#define DIM 1024
#define MTOT (NB * SEQ)   // 16384
constexpr size_t EL = (size_t)MTOT * DIM;

using u16x8  = __attribute__((ext_vector_type(8))) unsigned short;
using bf16x8 = __attribute__((ext_vector_type(8))) __bf16;
using f32x4  = __attribute__((ext_vector_type(4))) float;

__device__ __forceinline__ unsigned short f2bf(float f) {
  return __builtin_bit_cast(unsigned short, __float2bfloat16(f));  // native RNE cvt
}

__device__ __forceinline__ void gload16(const unsigned short* g, unsigned short* l) {
  __builtin_amdgcn_global_load_lds(
      (const __attribute__((address_space(1))) unsigned int*)g,
      (__attribute__((address_space(3))) unsigned int*)l, 16, 0, 0);
}
__device__ __forceinline__ void stage_half(const unsigned short* gsrc, size_t ld,
                                           unsigned short* ldst) {
  gload16(gsrc, ldst);
  gload16(gsrc + 64 * ld, ldst + 64 * 64);
}

#define BAR()   __builtin_amdgcn_s_barrier()
#define FENCE() asm volatile("" ::: "memory")

// ------- prep: x fp32->bf16, bias concat, lsum zero (one dispatch) -------
__global__ __launch_bounds__(256) void prep(const float* __restrict__ x,
                                            unsigned short* __restrict__ xb,
                                            const float* __restrict__ bq,
                                            const float* __restrict__ bk,
                                            const float* __restrict__ bv,
                                            float* __restrict__ bc,
                                            float* __restrict__ l) {
  const size_t gid = (size_t)blockIdx.x * 256 + threadIdx.x;
  const size_t i = gid * 4;
  float4 v = *(const float4*)(x + i);
  ushort4 o;
  o.x = f2bf(v.x); o.y = f2bf(v.y); o.z = f2bf(v.z); o.w = f2bf(v.w);
  *(ushort4*)(xb + i) = o;
  if (gid < MTOT) l[gid] = 0.f;
  if (gid < 3 * DIM)
    bc[gid] = gid < DIM ? bq[gid] : gid < 2 * DIM ? bk[gid - DIM] : bv[gid - 2 * DIM];
}

// ------- W fp32 [1024][1024] -> WT bf16, 3 matrices via blockIdx.z -------
__global__ __launch_bounds__(256) void transpose_w3(const float* __restrict__ Wq,
                                                    const float* __restrict__ Wk,
                                                    const float* __restrict__ Wv,
                                                    unsigned short* __restrict__ WT) {
  const float* W = blockIdx.z == 0 ? Wq : blockIdx.z == 1 ? Wk : Wv;
  unsigned short* O = WT + (size_t)blockIdx.z * DIM * DIM;
  __shared__ float tile[32][33];
  const int tx = threadIdx.x, ty = threadIdx.y;
  const int d0 = blockIdx.y * 32, e0 = blockIdx.x * 32;
#pragma unroll
  for (int j = 0; j < 32; j += 8)
    tile[ty + j][tx] = W[(size_t)(d0 + ty + j) * DIM + e0 + tx];
  __syncthreads();
#pragma unroll
  for (int j = 0; j < 32; j += 8)
    O[(size_t)(e0 + ty + j) * DIM + d0 + tx] = f2bf(tile[tx][ty + j]);
}

// ============ 256x256 8-phase BT-GEMM body: C[M,N] = A[M,K] * B^T ============
// 512 thr = 8 waves (2M x 4N); wave tile 128x64; BK=64; LDS 128KiB (2 K-tile bufs).
enum { EPI_QKV = 0, EPI_EXP = 1, EPI_PV = 2 };

template <int EPI>
__device__ __forceinline__ void gemm_body(
    const unsigned short* __restrict__ A, const unsigned short* __restrict__ B,
    void* __restrict__ C, const float* __restrict__ bias, float* __restrict__ lsum,
    int K, int lda, int ldb, int ldc, float scale,
    int row0, int col0, int bz, long sA, long sB, long sC) {
  __shared__ unsigned short sm[2][2][256 * 64];   // 128 KiB
  const int t    = threadIdx.x;
  const int lane = t & 63;
  const int wave = t >> 6;
  const int wm   = wave >> 2;          // 0..1  (M half)
  const int wn   = wave & 3;           // 0..3  (N quarter)
  const int fr   = lane & 15;
  const int g    = lane >> 4;          // k-group
  const int xr   = (fr & 7) << 4;      // read-side XOR

  const unsigned short* Ab = A + (size_t)bz * (size_t)sA;
  const unsigned short* Bb = B + (size_t)bz * (size_t)sB;

  const int srow = t >> 3;
  const int scol = ((((t & 7) << 4) ^ ((srow & 7) << 4)) >> 1);
  const unsigned short* gA = Ab + (size_t)(row0 + srow) * (size_t)lda + scol;
  const unsigned short* gB = Bb + (size_t)(col0 + srow) * (size_t)ldb + scol;

  const int arow = wm * 128 + fr;
  const int brow = wn * 64 + fr;
  const int c0 = (((g << 4)) ^ xr) >> 1;
  const int c1 = ((64 | (g << 4)) ^ xr) >> 1;

  f32x4 acc[8][4];
  const f32x4 z4 = {0.f, 0.f, 0.f, 0.f};
#pragma unroll
  for (int i = 0; i < 8; ++i)
#pragma unroll
    for (int j = 0; j < 4; ++j) acc[i][j] = z4;

  const int nt = K >> 6;

  stage_half(gA, lda, &sm[0][0][wave * 512]);
  stage_half(gA + 128 * (size_t)lda, lda, &sm[0][0][8192 + wave * 512]);
  stage_half(gB, ldb, &sm[0][1][wave * 512]);
  stage_half(gB + 128 * (size_t)ldb, ldb, &sm[0][1][8192 + wave * 512]);
  if (nt > 1) {
    stage_half(gB + 64, ldb, &sm[1][1][wave * 512]);
    stage_half(gB + 128 * (size_t)ldb + 64, ldb, &sm[1][1][8192 + wave * 512]);
    stage_half(gA + 64, lda, &sm[1][0][wave * 512]);
    asm volatile("s_waitcnt vmcnt(6)" ::: "memory");
  } else {
    asm volatile("s_waitcnt vmcnt(0)" ::: "memory");
  }
  BAR(); FENCE();

  bf16x8 a0[4][2], a1[4][2], b0[2][2], b1[2][2];

  for (int kt = 0; kt < nt; ++kt) {
    const int p = kt & 1;
    const unsigned short* As  = sm[p][0];
    const unsigned short* Bs2 = sm[p][1];

    // P1: read A0-3 + B0-1 (12), stage T(kt+1).A-hi
#pragma unroll
    for (int mi = 0; mi < 4; ++mi) {
      a0[mi][0] = *(const bf16x8*)(As + (arow + mi * 16) * 64 + c0);
      a0[mi][1] = *(const bf16x8*)(As + (arow + mi * 16) * 64 + c1);
    }
#pragma unroll
    for (int ni = 0; ni < 2; ++ni) {
      b0[ni][0] = *(const bf16x8*)(Bs2 + (brow + ni * 16) * 64 + c0);
      b0[ni][1] = *(const bf16x8*)(Bs2 + (brow + ni * 16) * 64 + c1);
    }
    if (kt + 1 < nt)
      stage_half(gA + 128 * (size_t)lda + (size_t)(kt + 1) * 64, lda,
                 &sm[p ^ 1][0][8192 + wave * 512]);
    FENCE(); BAR(); FENCE();
    __builtin_amdgcn_s_setprio(1);
#pragma unroll
    for (int mi = 0; mi < 4; ++mi)
#pragma unroll
      for (int ni = 0; ni < 2; ++ni) {
        acc[mi][ni] = __builtin_amdgcn_mfma_f32_16x16x32_bf16(a0[mi][0], b0[ni][0], acc[mi][ni], 0, 0, 0);
        acc[mi][ni] = __builtin_amdgcn_mfma_f32_16x16x32_bf16(a0[mi][1], b0[ni][1], acc[mi][ni], 0, 0, 0);
      }
    __builtin_amdgcn_s_setprio(0);
    FENCE(); BAR(); FENCE();

    // P2: read B2-3 (4)
#pragma unroll
    for (int ni = 0; ni < 2; ++ni) {
      b1[ni][0] = *(const bf16x8*)(Bs2 + (brow + (ni + 2) * 16) * 64 + c0);
      b1[ni][1] = *(const bf16x8*)(Bs2 + (brow + (ni + 2) * 16) * 64 + c1);
    }
    FENCE(); BAR(); FENCE();
    __builtin_amdgcn_s_setprio(1);
#pragma unroll
    for (int mi = 0; mi < 4; ++mi)
#pragma unroll
      for (int ni = 0; ni < 2; ++ni) {
        acc[mi][ni + 2] = __builtin_amdgcn_mfma_f32_16x16x32_bf16(a0[mi][0], b1[ni][0], acc[mi][ni + 2], 0, 0, 0);
        acc[mi][ni + 2] = __builtin_amdgcn_mfma_f32_16x16x32_bf16(a0[mi][1], b1[ni][1], acc[mi][ni + 2], 0, 0, 0);
      }
    __builtin_amdgcn_s_setprio(0);
    FENCE(); BAR(); FENCE();

    // P3: read A4-7 (8), stage T(kt+2).B-lo
#pragma unroll
    for (int mi = 0; mi < 4; ++mi) {
      a1[mi][0] = *(const bf16x8*)(As + (arow + (mi + 4) * 16) * 64 + c0);
      a1[mi][1] = *(const bf16x8*)(As + (arow + (mi + 4) * 16) * 64 + c1);
    }
    if (kt + 2 < nt)
      stage_half(gB + (size_t)(kt + 2) * 64, ldb, &sm[p][1][wave * 512]);
    FENCE(); BAR(); FENCE();
    __builtin_amdgcn_s_setprio(1);
#pragma unroll
    for (int mi = 0; mi < 4; ++mi)
#pragma unroll
      for (int ni = 0; ni < 2; ++ni) {
        acc[mi + 4][ni] = __builtin_amdgcn_mfma_f32_16x16x32_bf16(a1[mi][0], b0[ni][0], acc[mi + 4][ni], 0, 0, 0);
        acc[mi + 4][ni] = __builtin_amdgcn_mfma_f32_16x16x32_bf16(a1[mi][1], b0[ni][1], acc[mi + 4][ni], 0, 0, 0);
      }
    __builtin_amdgcn_s_setprio(0);
    FENCE(); BAR(); FENCE();

    // P4: stage T(kt+2).{B-hi,A-lo}; counted vmcnt; MFMA q3
    if (kt + 2 < nt) {
      stage_half(gB + 128 * (size_t)ldb + (size_t)(kt + 2) * 64, ldb,
                 &sm[p][1][8192 + wave * 512]);
      stage_half(gA + (size_t)(kt + 2) * 64, lda, &sm[p][0][wave * 512]);
      asm volatile("s_waitcnt vmcnt(6)" ::: "memory");
    } else {
      asm volatile("s_waitcnt vmcnt(0)" ::: "memory");
    }
    FENCE(); BAR(); FENCE();
    __builtin_amdgcn_s_setprio(1);
#pragma unroll
    for (int mi = 0; mi < 4; ++mi)
#pragma unroll
      for (int ni = 0; ni < 2; ++ni) {
        acc[mi + 4][ni + 2] = __builtin_amdgcn_mfma_f32_16x16x32_bf16(a1[mi][0], b1[ni][0], acc[mi + 4][ni + 2], 0, 0, 0);
        acc[mi + 4][ni + 2] = __builtin_amdgcn_mfma_f32_16x16x32_bf16(a1[mi][1], b1[ni][1], acc[mi + 4][ni + 2], 0, 0, 0);
      }
    __builtin_amdgcn_s_setprio(0);
    FENCE(); BAR(); FENCE();
  }

  // ===================== LDS-staged coalesced epilogues =====================
  char* Lb = (char*)&sm[0][0][0];
  const int rb = (lane >> 4) * 4;

  if constexpr (EPI == EPI_QKV) {
    const int which = col0 >> 10;            // 0=Q 1=K 2=V
    const int lc0   = col0 & 1023;
    unsigned short* Co = (unsigned short*)C + (size_t)which * EL;
    if (which < 2) {
      float bb[4];
#pragma unroll
      for (int ni = 0; ni < 4; ++ni) bb[ni] = bias[col0 + wn * 64 + ni * 16 + fr];
#pragma unroll
      for (int mi = 0; mi < 8; ++mi) {
        const int r0 = wm * 128 + mi * 16 + rb;
#pragma unroll
        for (int ni = 0; ni < 4; ++ni) {
          const int c = wn * 64 + ni * 16 + fr;
#pragma unroll
          for (int j = 0; j < 4; ++j) {
            const int r = r0 + j;
            *(unsigned short*)(Lb + r * 512 + ((c * 2) ^ ((r & 7) << 4))) =
                f2bf(acc[mi][ni][j] + bb[ni]);
          }
        }
      }
      __syncthreads();
#pragma unroll 4
      for (int i = 0; i < 16; ++i) {
        const int G = i * 512 + t;
        const int r = G >> 5, c16 = G & 31;
        u16x8 v = *(const u16x8*)(Lb + r * 512 + ((c16 * 16) ^ ((r & 7) << 4)));
        *(u16x8*)(Co + (size_t)(row0 + r) * DIM + lc0 + c16 * 8) = v;
      }
    } else {
      // V: store transposed through col-major LDS tile
#pragma unroll
      for (int ni = 0; ni < 4; ++ni) {
        const int c = wn * 64 + ni * 16 + fr;
        const float bb = bias[col0 + c];
#pragma unroll
        for (int mi = 0; mi < 8; ++mi) {
          const int r0 = wm * 128 + mi * 16 + rb;
          ushort4 pk;
          pk.x = f2bf(acc[mi][ni][0] + bb);
          pk.y = f2bf(acc[mi][ni][1] + bb);
          pk.z = f2bf(acc[mi][ni][2] + bb);
          pk.w = f2bf(acc[mi][ni][3] + bb);
          *(ushort4*)(Lb + c * 512 + ((r0 * 2) ^ ((c & 7) << 4))) = pk;
        }
      }
      __syncthreads();
#pragma unroll 4
      for (int i = 0; i < 16; ++i) {
        const int G = i * 512 + t;
        const int e = G >> 5, m16 = G & 31;
        u16x8 v = *(const u16x8*)(Lb + e * 512 + ((m16 * 16) ^ ((e & 7) << 4)));
        *(u16x8*)(Co + (size_t)(lc0 + e) * MTOT + row0 + m16 * 8) = v;
      }
    }
  } else if constexpr (EPI == EPI_EXP) {
    // E = exp2(acc*scale); row sums reduced from registers (shfl), then
    // coalesced E store through LDS.
#pragma unroll
    for (int mi = 0; mi < 8; ++mi)
#pragma unroll
      for (int ni = 0; ni < 4; ++ni)
#pragma unroll
        for (int j = 0; j < 4; ++j)
          acc[mi][ni][j] = exp2f(acc[mi][ni][j] * scale);

    // register rowsum: Σni (4 adds) then shfl_xor 1,2,4,8 within 16-lane group
#pragma unroll
    for (int mi = 0; mi < 8; ++mi)
#pragma unroll
      for (int j = 0; j < 4; ++j) {
        float s = acc[mi][0][j] + acc[mi][1][j] + acc[mi][2][j] + acc[mi][3][j];
        s += __shfl_xor(s, 1);
        s += __shfl_xor(s, 2);
        s += __shfl_xor(s, 4);
        s += __shfl_xor(s, 8);
        if (fr == 0)
          atomicAdd(&lsum[(size_t)bz * SEQ + row0 + wm * 128 + mi * 16 + rb + j], s);
      }

#pragma unroll
    for (int mi = 0; mi < 8; ++mi) {
      const int r0 = wm * 128 + mi * 16 + rb;
#pragma unroll
      for (int ni = 0; ni < 4; ++ni) {
        const int c = wn * 64 + ni * 16 + fr;
#pragma unroll
        for (int j = 0; j < 4; ++j) {
          const int r = r0 + j;
          *(unsigned short*)(Lb + r * 512 + ((c * 2) ^ ((r & 7) << 4))) =
              f2bf(acc[mi][ni][j]);
        }
      }
    }
    __syncthreads();
    unsigned short* Co = (unsigned short*)C + (size_t)bz * (size_t)sC;
#pragma unroll 4
    for (int i = 0; i < 16; ++i) {
      const int G = i * 512 + t;
      const int r = G >> 5, c16 = G & 31;
      u16x8 v = *(const u16x8*)(Lb + r * 512 + ((c16 * 16) ^ ((r & 7) << 4)));
      *(u16x8*)(Co + (size_t)(row0 + r) * (size_t)ldc + col0 + c16 * 8) = v;
    }
  } else {  // EPI_PV: fp32 out / lsum[row], two 128-row halves through LDS
    float* Co = (float*)C + (size_t)bz * (size_t)sC;
#pragma unroll
    for (int h = 0; h < 2; ++h) {
      if (h) __syncthreads();
      if (wm == h) {
#pragma unroll
        for (int mi = 0; mi < 8; ++mi) {
          const int r0 = mi * 16 + rb;
#pragma unroll
          for (int ni = 0; ni < 4; ++ni) {
            const int c = wn * 64 + ni * 16 + fr;
#pragma unroll
            for (int j = 0; j < 4; ++j) {
              const int r = r0 + j;
              *(float*)(Lb + r * 1024 + ((c * 4) ^ ((r & 7) << 4))) = acc[mi][ni][j];
            }
          }
        }
      }
      __syncthreads();
#pragma unroll 4
      for (int i = 0; i < 16; ++i) {
        const int G = i * 512 + t;
        const int r = G >> 6, c4 = G & 63;
        f32x4 v = *(const f32x4*)(Lb + r * 1024 + ((c4 * 16) ^ ((r & 7) << 4)));
        const size_t grow = (size_t)row0 + h * 128 + r;
        const float inv = 1.0f / lsum[(size_t)bz * SEQ + grow];
        v *= inv;
        *(f32x4*)(Co + grow * (size_t)ldc + col0 + c4 * 4) = v;
      }
    }
  }
}

// ---------------- named wrappers (distinct rocprof attribution) ----------------
__global__ __launch_bounds__(512, 2) void gemm_qkv(
    const unsigned short* __restrict__ A, const unsigned short* __restrict__ B,
    unsigned short* __restrict__ C, const float* __restrict__ bcat) {
  gemm_body<EPI_QKV>(A, B, C, bcat, nullptr, DIM, DIM, DIM, DIM, 1.f,
                     (int)blockIdx.x * 256, (int)blockIdx.y * 256, 0, 0, 0, 0);
}

__global__ __launch_bounds__(512, 2) void gemm_exp(
    const unsigned short* __restrict__ A, const unsigned short* __restrict__ B,
    unsigned short* __restrict__ C, float* __restrict__ lsum) {
  // E = exp2(S * log2e/32); scale folds 1/sqrt(1024) and log2(e)
  gemm_body<EPI_EXP>(A, B, C, nullptr, lsum, DIM, DIM, DIM, SEQ, 0.04508422f,
                     (int)blockIdx.x * 256, (int)blockIdx.y * 256, (int)blockIdx.z,
                     (long)SEQ * DIM, (long)SEQ * DIM, (long)SEQ * SEQ);
}

__global__ __launch_bounds__(512, 2) void gemm_pv(
    const unsigned short* __restrict__ A, const unsigned short* __restrict__ B,
    float* __restrict__ C, float* __restrict__ lsum) {
  // grid (4,16,NB) flat-swizzled so each XCD gets 8 row-tiles x 4 col-tiles
  const int flat = (int)blockIdx.x +
                   (int)gridDim.x * ((int)blockIdx.y + (int)gridDim.y * (int)blockIdx.z);
  const int nf  = (flat & 7) * 32 + (flat >> 3);   // 256 = 8 XCD x 32, bijective
  const int b   = nf >> 6;
  const int rc  = nf & 63;
  const int row = rc >> 2, col = rc & 3;
  gemm_body<EPI_PV>(A, B, C, nullptr, lsum, SEQ, SEQ, MTOT, DIM, 1.f,
                    row * 256, col * 256, b,
                    (long)SEQ * SEQ, (long)SEQ, (long)SEQ * DIM);
}

extern "C" void kernel_launch(void* const* d_in, const int* in_sizes, int n_in,
                              void* d_out, int out_size, void* d_ws, size_t ws_size,
                              hipStream_t stream) {
  (void)in_sizes; (void)n_in; (void)out_size; (void)ws_size;
  const float* x  = (const float*)d_in[0];
  const float* Wq = (const float*)d_in[1];
  const float* bq = (const float*)d_in[2];
  const float* Wk = (const float*)d_in[3];
  const float* bk = (const float*)d_in[4];
  const float* Wv = (const float*)d_in[5];
  const float* bv = (const float*)d_in[6];
  float* out = (float*)d_out;

  const size_t SALL = (size_t)NB * SEQ * SEQ;
  unsigned short* Q  = (unsigned short*)d_ws;
  unsigned short* Km = Q + EL;
  unsigned short* VT = Km + EL;                  // transposed: VT[e][b*SEQ+s]
  unsigned short* Sb = VT + EL;                  // E = exp(S/32), unnormalized
  unsigned short* WT = Sb + SALL;                // [3072][1024] = WqT|WkT|WvT
  float*          l  = (float*)(WT + (size_t)3 * DIM * DIM);   // [MTOT] row sums
  float*          bc = l + MTOT;                 // bcat[3072]
  unsigned short* xb = Sb;                       // x_bf16 overlaps E (dead after proj)

  prep<<<dim3(EL / 1024), dim3(256), 0, stream>>>(x, xb, bq, bk, bv, bc, l);
  transpose_w3<<<dim3(32, 32, 3), dim3(32, 8), 0, stream>>>(Wq, Wk, Wv, WT);

  // fused QKV projection: [16384,1024] x [3072,1024]^T, epilogue routes Q/K/VT
  gemm_qkv<<<dim3(MTOT / 256, 3 * DIM / 256), 512, 0, stream>>>(xb, WT, Q, bc);

  // E = exp(QK^T/32) (bf16) + row sums l (register shfl reduce + atomics)
  gemm_exp<<<dim3(SEQ / 256, SEQ / 256, NB), 512, 0, stream>>>(Q, Km, Sb, l);

  // O = (E · V) / l  (fp32 out), XCD-swizzled grid
  gemm_pv<<<dim3(DIM / 256, SEQ / 256, NB), 512, 0, stream>>>(Sb, VT, out, l);
}